// Round 9
// baseline (584.952 us; speedup 1.0000x reference)
//
#include <hip/hip_runtime.h>
#include <math.h>

#define BATCH 8
#define CDIM 768
#define NTOK 1024
#define NH 12
#define HDIM 64
#define QKVN 2304

typedef __attribute__((ext_vector_type(8))) short bf16x8;
typedef __attribute__((ext_vector_type(4))) float f32x4;

__device__ inline short f2bf(float f) {
    union { float f; unsigned u; } v; v.f = f;
    unsigned r = (v.u + 0x7FFF + ((v.u >> 16) & 1)) >> 16;
    return (short)r;
}

__device__ inline unsigned pack2bf(float lo, float hi) {
    return (unsigned)(unsigned short)f2bf(lo) | ((unsigned)(unsigned short)f2bf(hi) << 16);
}

// async global->LDS DMA, 16 B per lane; lptr must be the WAVE-uniform base,
// lane l writes lptr + l*16 bytes (m97 pattern). Global src is per-lane.
__device__ inline void async_copy16(const short* g, short* l) {
    __builtin_amdgcn_global_load_lds(
        (const __attribute__((address_space(1))) void*)g,
        (__attribute__((address_space(3))) void*)l, 16, 0, 0);
}

// ---------------- fused prep: pack qkv weights + 4 weight transposes +
// bias pack + input transpose, one launch ----------------
__global__ __launch_bounds__(256) void k_prep(
    const float* __restrict__ wq1, const float* __restrict__ wk1, const float* __restrict__ wv1,
    const float* __restrict__ wq2, const float* __restrict__ wk2, const float* __restrict__ wv2,
    const float* __restrict__ wo1, const float* __restrict__ wo2,
    const float* __restrict__ cnw1, const float* __restrict__ cnw2,
    const float* __restrict__ bq1, const float* __restrict__ bk1, const float* __restrict__ bv1,
    const float* __restrict__ bq2, const float* __restrict__ bk2, const float* __restrict__ bv2,
    const float* __restrict__ dec,
    short* __restrict__ Wqkv1, short* __restrict__ Wqkv2,
    short* __restrict__ WoT1, short* __restrict__ WoT2,
    short* __restrict__ W1T, short* __restrict__ W2T,
    float* __restrict__ bqkv1, float* __restrict__ bqkv2,
    float* __restrict__ A0, short* __restrict__ Xb) {
    __shared__ float sh[64 * 65];
    int bid = blockIdx.x;
    int t = threadIdx.x;
    if (bid < 864) {
        // pack per-head qkv weights -> [2304,768] bf16
        int bx = bid % 12, z = bid / 12;
        int set = z / 36, rem = z % 36, sect = rem / 12, hh = rem % 12;
        const float* srcs[6] = {wq1, wk1, wv1, wq2, wk2, wv2};
        const float* src = srcs[set * 3 + sect] + (size_t)hh * 768 * 64;
        short* dst = (set ? Wqkv2 : Wqkv1) + ((size_t)sect * 768 + hh * 64) * 768;
        int k0 = bx * 64;
#pragma unroll
        for (int p = 0; p < 16; ++p) {
            int gid = t + p * 256;
            int r = gid >> 6, c = gid & 63;
            sh[r * 65 + c] = src[(size_t)(k0 + r) * 64 + c];
        }
        __syncthreads();
#pragma unroll
        for (int p = 0; p < 16; ++p) {
            int gid = t + p * 256;
            int d = gid >> 6, kk = gid & 63;
            dst[(size_t)d * 768 + k0 + kk] = f2bf(sh[kk * 65 + d]);
        }
    } else if (bid < 6624) {
        // weight transpose fp32 [R,C] -> bf16 [C,R]
        int r = bid - 864;
        const float* src; short* dst; int R, C, bx, by;
        if (r < 576)       { src = wo1;  dst = WoT1; R = 768;  C = 768;  bx = r % 24; by = r / 24; }
        else if (r < 1152) { int s = r - 576;  src = wo2;  dst = WoT2; R = 768;  C = 768;  bx = s % 24; by = s / 24; }
        else if (r < 3456) { int s = r - 1152; src = cnw1; dst = W1T;  R = 768;  C = 3072; bx = s % 96; by = s / 96; }
        else               { int s = r - 3456; src = cnw2; dst = W2T;  R = 3072; C = 768;  bx = s % 24; by = s / 24; }
        int c0 = bx * 32, r0 = by * 32, tx = t & 31, ty = t >> 5;
#pragma unroll
        for (int p = 0; p < 4; ++p)
            sh[(ty + p * 8) * 33 + tx] = src[(size_t)(r0 + ty + p * 8) * C + c0 + tx];
        __syncthreads();
#pragma unroll
        for (int p = 0; p < 4; ++p)
            dst[(size_t)(c0 + ty + p * 8) * R + r0 + tx] = f2bf(sh[tx * 33 + ty + p * 8]);
    } else if (bid < 6642) {
        // pack biases
        int tid = (bid - 6624) * 256 + t;
        if (tid < 4608) {
            int set = tid / 2304, n = tid % 2304;
            int sect = n / 768, rem = n % 768;
            const float* srcs[6] = {bq1, bk1, bv1, bq2, bk2, bv2};
            float v = srcs[set * 3 + sect][rem];
            (set ? bqkv2 : bqkv1)[n] = v;
        }
    } else {
        // transpose [B,C,N] -> [B,N,C], fp32 + bf16 mirror
        int r = bid - 6642;
        int bx = r % 32, by = (r / 32) % 24, bz = r / 768;
        int n0 = bx * 32, c0 = by * 32, tx = t & 31, ty = t >> 5;
#pragma unroll
        for (int p = 0; p < 4; ++p) {
            int c = c0 + ty + p * 8;
            sh[(ty + p * 8) * 33 + tx] = dec[((size_t)bz * CDIM + c) * NTOK + n0 + tx];
        }
        __syncthreads();
#pragma unroll
        for (int p = 0; p < 4; ++p) {
            int n = n0 + ty + p * 8;
            float val = sh[tx * 33 + ty + p * 8];
            size_t idx = ((size_t)bz * NTOK + n) * CDIM + c0 + tx;
            A0[idx] = val;
            Xb[idx] = f2bf(val);
        }
    }
}

// ---------------- generic bf16 MFMA GEMM, 128xBN tile, BK=32 ----------------
// 3-stage ring with COUNTED vmcnt (T4): loads for tile t+2 issued during tile
// t; per-tile gate is s_waitcnt vmcnt(LPI) (tile t+1's LPI loads stay in
// flight - never drained to 0 inside the loop) then s_barrier. Each wave
// gates on its OWN loads before the barrier => barrier-exit = collective
// completion. Buffer (t+2)%3 overwrites tile t-1 (reads retired at barrier t).
// Chunk-XOR swizzle (proven 0-conflict): source chunk ^= (row>>1)&3, read
// chunk = quad ^ ((l15>>1)&3). Read addresses and MFMA order identical to the
// proven 2-stage kernel -> bit-identical results.
// A [M,K] bf16 row-major; Bt [N,K] bf16 row-major (i.e. B transposed)
#define GM_FINAL 0
#define GM_PROJ  1
#define GM_GELU  2
#define GM_BF16  3

template<int MODE, int BN>
__global__ __launch_bounds__(256) void k_gemm_mfma(
    const short* __restrict__ A, const short* __restrict__ Bt,
    const float* __restrict__ bias, const float* __restrict__ resid,
    const float* __restrict__ rscale, const float* __restrict__ alph,
    float* __restrict__ outF, short* __restrict__ outB, int M, int N, int K) {
    constexpr int NT = BN / 32;     // 16-col tiles per wave
    constexpr int BP = BN / 64;     // B staging passes per tile
    constexpr int ASTG = 128 * 32;  // shorts per A stage
    constexpr int BSTG = BN * 32;   // shorts per B stage
    constexpr int SSTG = ASTG + BSTG;
    constexpr int STAGE = 3 * SSTG;
    constexpr int FINALS = (MODE == GM_FINAL) ? 64 * 132 * 2 : 0; // 64 cols x 132-stride floats
    constexpr int SMEM = STAGE > FINALS ? STAGE : FINALS;
    __shared__ short smem[SMEM];
    int t = threadIdx.x;
    int w = t >> 6, lane = t & 63, l15 = lane & 15, quad = lane >> 4;
    int r0 = blockIdx.x * 128, n0 = blockIdx.y * BN;
    int wr = (w >> 1) * 64, wc = (w & 1) * (BN / 2);
    f32x4 acc[4][NT];
#pragma unroll
    for (int i = 0; i < 4; ++i)
#pragma unroll
        for (int j = 0; j < NT; ++j) acc[i][j] = (f32x4){0.f, 0.f, 0.f, 0.f};
    // staging: row = t>>2, chunk = t&3, source chunk XOR-swizzled by (row>>1)&3
    int sr = t >> 2, sc = ((t & 3) ^ ((sr >> 1) & 3)) * 8;
    const short* Ag = A + (size_t)(r0 + sr) * K + sc;
    const short* Bg = Bt + (size_t)(n0 + sr) * K + sc;
    // read-side swizzle: physical chunk = quad ^ ((l15>>1)&3)
    int rsw = ((quad ^ ((l15 >> 1) & 3)) << 3);
    int wo = w * 512;

    auto ISSUE = [&](int s, int k0) {
        short* base = smem + s * SSTG;
#pragma unroll
        for (int p = 0; p < 2; ++p)
            async_copy16(Ag + k0 + (size_t)p * 64 * K, base + p * 2048 + wo);
#pragma unroll
        for (int p = 0; p < BP; ++p)
            async_copy16(Bg + k0 + (size_t)p * 64 * K, base + ASTG + p * 2048 + wo);
    };
    int NI = K >> 5;   // 32-wide K steps
    // prologue: 2 tiles in flight
    ISSUE(0, 0);
    ISSUE(1, 32);
    int cur = 0;
    for (int it = 0; it < NI; ++it) {
        if (it + 1 < NI) {
            // wait this wave's tile-it loads; tile it+1's LPI loads stay in flight
            if constexpr (BP == 2) asm volatile("s_waitcnt vmcnt(4)" ::: "memory");
            else                   asm volatile("s_waitcnt vmcnt(3)" ::: "memory");
        } else {
            asm volatile("s_waitcnt vmcnt(0)" ::: "memory");
        }
        __builtin_amdgcn_s_barrier();
        __builtin_amdgcn_sched_barrier(0);
        if (it + 2 < NI) {
            int nxt = cur + 2; if (nxt >= 3) nxt -= 3;
            ISSUE(nxt, (it + 2) * 32);
        }
        short* base = smem + cur * SSTG;
        bf16x8 af[4], bf[NT];
#pragma unroll
        for (int i = 0; i < 4; ++i)
            af[i] = *(const bf16x8*)&base[(wr + i * 16 + l15) * 32 + rsw];
#pragma unroll
        for (int j = 0; j < NT; ++j)
            bf[j] = *(const bf16x8*)&base[ASTG + (wc + j * 16 + l15) * 32 + rsw];
#pragma unroll
        for (int i = 0; i < 4; ++i)
#pragma unroll
            for (int j = 0; j < NT; ++j)
                acc[i][j] = __builtin_amdgcn_mfma_f32_16x16x32_bf16(af[i], bf[j], acc[i][j], 0, 0, 0);
        if (++cur == 3) cur = 0;
    }
    if (MODE == GM_FINAL) {
        // fused: val = rscale*val(+bias) + alph*resid; write transposed [B,C,N] via LDS
        __syncthreads();
        float* T = (float*)smem;
#pragma unroll
        for (int i = 0; i < 4; ++i)
#pragma unroll
            for (int j = 0; j < NT; ++j)
#pragma unroll
                for (int rr = 0; rr < 4; ++rr) {
                    int rl = wr + i * 16 + quad * 4 + rr;   // 0..127
                    int cl = wc + j * 16 + l15;             // 0..63
                    int row = r0 + rl, col = n0 + cl;
                    float val = acc[i][j][rr] + bias[col];
                    val = rscale[col] * val + alph[col] * resid[(size_t)row * N + col];
                    T[cl * 132 + rl] = val;
                }
        __syncthreads();
        int c = t >> 2, qo = (t & 3) * 32;
        int b = r0 >> 10, tokbase = r0 & 1023;
        float* obase = outF + ((size_t)(b * 768 + n0 + c)) * 1024 + tokbase + qo;
#pragma unroll
        for (int ii = 0; ii < 8; ++ii)
            *(float4*)&obase[ii * 4] = *(float4*)&T[c * 132 + qo + ii * 4];
        return;
    }
#pragma unroll
    for (int i = 0; i < 4; ++i)
#pragma unroll
        for (int j = 0; j < NT; ++j)
#pragma unroll
            for (int rr = 0; rr < 4; ++rr) {
                int row = r0 + wr + i * 16 + quad * 4 + rr;
                int col = n0 + wc + j * 16 + l15;
                float val = acc[i][j][rr] + bias[col];
                if (MODE == GM_PROJ) {
                    val += rscale[col] * resid[(size_t)row * N + col];
                    outF[(size_t)row * N + col] = val;
                } else if (MODE == GM_GELU) {
                    // tanh-form GELU via hw exp2/rcp: x*sigmoid(1.595769*(x+0.044715x^3))
                    float u = val * (1.0f + 0.044715f * val * val);
                    float zz = __builtin_amdgcn_rcpf(
                        1.0f + __builtin_amdgcn_exp2f(-2.3022082f * u));
                    outB[(size_t)row * N + col] = f2bf(val * zz);
                } else {  // GM_BF16: plain bf16 row-major C
                    outB[(size_t)row * N + col] = f2bf(val);
                }
            }
}

// ---------------- MFMA sigmoid attention, v4 (proven R5) ----------------
// per (b,h): O = sigmoid(QK^T/8) V ; q/k/v = column sections of the packed
// [B*N, 2304] QKV matrix (row stride 2304); O -> [B,N,C] bf16
__global__ __launch_bounds__(256, 3) void k_attn_mfma(
    const short* __restrict__ q, const short* __restrict__ k,
    const short* __restrict__ v, short* __restrict__ o) {
    __shared__ short Ks[2][64 * 64];   // chunk16B c holds logical chunk c^(row&7)
    __shared__ short Vt[2][64][72];    // V^T [d][tok], padded
    __shared__ short Ps[128][72];      // P [q][key], rows wave-private
    int t = threadIdx.x;
    int w = t >> 6, lane = t & 63, l15 = lane & 15, quad = lane >> 4;
    int flat = blockIdx.x + (blockIdx.y << 3) + blockIdx.z * 96;
    int xcd = flat & 7, slot = flat >> 3;
    int qb = slot & 7, grp = xcd * 12 + (slot >> 3);
    int h = grp % 12, b = grp / 12;
    int q0 = qb * 128;
    size_t base = ((size_t)b * NTOK) * QKVN + h * 64;
    const short* qp = q + base;
    const short* kp = k + base;
    const short* vp = v + base;

    bf16x8 qf[2][2];
#pragma unroll
    for (int nq = 0; nq < 2; ++nq)
#pragma unroll
        for (int kc = 0; kc < 2; ++kc)
            qf[nq][kc] = *(const bf16x8*)&qp[(size_t)(q0 + w * 32 + nq * 16 + l15) * QKVN + kc * 32 + quad * 8];

    int r8 = lane >> 3;
    const short* kg = kp + (size_t)r8 * QKVN + (((lane & 7) ^ r8) << 3);
    int vtok = t & 63, vd0 = (t >> 6) * 8;

    f32x4 oacc[4][2];
#pragma unroll
    for (int dt = 0; dt < 4; ++dt)
#pragma unroll
        for (int nq = 0; nq < 2; ++nq) oacc[dt][nq] = (f32x4){0.f, 0.f, 0.f, 0.f};

#pragma unroll
    for (int p = 0; p < 2; ++p)
        async_copy16(kg + (size_t)(p * 32 + w * 8) * QKVN, &Ks[0][(p * 32 + w * 8) * 64]);
    {
        bf16x8 v0 = *(const bf16x8*)&vp[(size_t)vtok * QKVN + vd0];
        bf16x8 v1 = *(const bf16x8*)&vp[(size_t)vtok * QKVN + vd0 + 32];
#pragma unroll
        for (int j = 0; j < 8; ++j) {
            Vt[0][vd0 + j][vtok] = v0[j];
            Vt[0][vd0 + 32 + j][vtok] = v1[j];
        }
    }

    short* prow0 = &Ps[w * 32 + l15][0];
    short* prow1 = &Ps[w * 32 + 16 + l15][0];

    for (int kt = 0; kt < 16; ++kt) {
        int cur = kt & 1, nxt = cur ^ 1;
        __syncthreads();
        bf16x8 vv0, vv1;
        if (kt < 15) {
            const short* kgn = kg + (size_t)((kt + 1) * 64) * QKVN;
#pragma unroll
            for (int p = 0; p < 2; ++p)
                async_copy16(kgn + (size_t)(p * 32 + w * 8) * QKVN, &Ks[nxt][(p * 32 + w * 8) * 64]);
            vv0 = *(const bf16x8*)&vp[((size_t)((kt + 1) * 64 + vtok)) * QKVN + vd0];
            vv1 = *(const bf16x8*)&vp[((size_t)((kt + 1) * 64 + vtok)) * QKVN + vd0 + 32];
        }
        f32x4 sacc[4][2];
#pragma unroll
        for (int mk = 0; mk < 4; ++mk)
#pragma unroll
            for (int nq = 0; nq < 2; ++nq) sacc[mk][nq] = (f32x4){0.f, 0.f, 0.f, 0.f};
        __builtin_amdgcn_s_setprio(1);
#pragma unroll
        for (int mk = 0; mk < 4; ++mk)
#pragma unroll
            for (int kc = 0; kc < 2; ++kc) {
                bf16x8 kf = *(const bf16x8*)&Ks[cur][(mk * 16 + l15) * 64 + (((kc * 4 + quad) ^ (l15 & 7)) << 3)];
#pragma unroll
                for (int nq = 0; nq < 2; ++nq)
                    sacc[mk][nq] = __builtin_amdgcn_mfma_f32_16x16x32_bf16(kf, qf[nq][kc], sacc[mk][nq], 0, 0, 0);
            }
        __builtin_amdgcn_s_setprio(0);
#pragma unroll
        for (int mk = 0; mk < 4; ++mk)
#pragma unroll
            for (int nq = 0; nq < 2; ++nq) {
                float z[4];
#pragma unroll
                for (int rr = 0; rr < 4; ++rr)
                    z[rr] = __builtin_amdgcn_rcpf(
                        1.0f + __builtin_amdgcn_exp2f(sacc[mk][nq][rr] * -0.18033688011112042f));
                unsigned* pw = (unsigned*)((nq ? prow1 : prow0) + mk * 16 + quad * 4);
                pw[0] = pack2bf(z[0], z[1]);
                pw[1] = pack2bf(z[2], z[3]);
            }
        if (kt < 15) {
#pragma unroll
            for (int j = 0; j < 8; ++j) {
                Vt[nxt][vd0 + j][vtok] = vv0[j];
                Vt[nxt][vd0 + 32 + j][vtok] = vv1[j];
            }
        }
        asm volatile("s_waitcnt lgkmcnt(0)" ::: "memory");
        __builtin_amdgcn_sched_barrier(0);
        bf16x8 pf[2][2];
#pragma unroll
        for (int kc = 0; kc < 2; ++kc)
#pragma unroll
            for (int nq = 0; nq < 2; ++nq)
                pf[kc][nq] = *(const bf16x8*)((nq ? prow1 : prow0) + kc * 32 + quad * 8);
        __builtin_amdgcn_s_setprio(1);
#pragma unroll
        for (int dt = 0; dt < 4; ++dt)
#pragma unroll
            for (int kc = 0; kc < 2; ++kc) {
                bf16x8 vf = *(const bf16x8*)&Vt[cur][dt * 16 + l15][kc * 32 + quad * 8];
#pragma unroll
                for (int nq = 0; nq < 2; ++nq)
                    oacc[dt][nq] = __builtin_amdgcn_mfma_f32_16x16x32_bf16(vf, pf[kc][nq], oacc[dt][nq], 0, 0, 0);
            }
        __builtin_amdgcn_s_setprio(0);
    }
#pragma unroll
    for (int dt = 0; dt < 4; ++dt)
#pragma unroll
        for (int nq = 0; nq < 2; ++nq) {
            int tok = q0 + w * 32 + nq * 16 + l15;
            int c = h * 64 + dt * 16 + quad * 4;
            unsigned* op = (unsigned*)&o[((size_t)b * NTOK + tok) * CDIM + c];
            op[0] = pack2bf(oacc[dt][nq][0], oacc[dt][nq][1]);
            op[1] = pack2bf(oacc[dt][nq][2], oacc[dt][nq][3]);
        }
}

// ---------------- depthwise conv, register sliding window (fp32) ----------------
template<int K>
__global__ __launch_bounds__(256) void k_dwconv_t(
    const float* __restrict__ in, const float* __restrict__ w,
    const float* __restrict__ bias, float* __restrict__ out) {
    constexpr int PAD = K / 2;
    constexpr int KK = K * K;
    int t = threadIdx.x;
    int c = blockIdx.y * 64 + (t & 63);
    int j = blockIdx.x * 4 + (t >> 6);
    int b = blockIdx.z;
    float wr[KK];
#pragma unroll
    for (int qq = 0; qq < KK; ++qq) wr[qq] = w[(size_t)c * KK + qq];
    float bsv = bias[c];
    const float* base = in + (size_t)b * NTOK * CDIM + c;
    float win[K][K];
#pragma unroll
    for (int s = 1; s < K; ++s) {
        int ii = s - 1 - PAD;
#pragma unroll
        for (int qq = 0; qq < K; ++qq) {
            int jj = j - PAD + qq;
            win[s][qq] = (ii >= 0 && jj >= 0 && jj < 32)
                         ? base[(size_t)(ii * 32 + jj) * CDIM] : 0.0f;
        }
    }
#pragma unroll
    for (int i = 0; i < 32; ++i) {
#pragma unroll
        for (int r = 0; r < K - 1; ++r)
#pragma unroll
            for (int qq = 0; qq < K; ++qq) win[r][qq] = win[r + 1][qq];
        int ii = i + PAD;
#pragma unroll
        for (int qq = 0; qq < K; ++qq) {
            int jj = j - PAD + qq;
            win[K - 1][qq] = (ii < 32 && jj >= 0 && jj < 32)
                             ? base[(size_t)(ii * 32 + jj) * CDIM] : 0.0f;
        }
        float acc = bsv;
#pragma unroll
        for (int r = 0; r < K; ++r)
#pragma unroll
            for (int qq = 0; qq < K; ++qq)
                acc = fmaf(win[r][qq], wr[r * K + qq], acc);
        out[((size_t)b * NTOK + i * 32 + j) * CDIM + c] = acc;
    }
}

// ---------------- layernorm over C=768, nullable fp32/bf16 outputs ----------------
__global__ __launch_bounds__(256) void k_ln(
    const float* __restrict__ in, const float* __restrict__ g,
    const float* __restrict__ b, float* __restrict__ outF, short* __restrict__ outB) {
    int row = blockIdx.x;
    const float* xr = in + (size_t)row * CDIM;
    int t = threadIdx.x;
    float x0 = xr[t], x1 = xr[t + 256], x2 = xr[t + 512];
    float s = x0 + x1 + x2;
    float sq = x0 * x0 + x1 * x1 + x2 * x2;
#pragma unroll
    for (int off = 32; off > 0; off >>= 1) {
        s += __shfl_down(s, off);
        sq += __shfl_down(sq, off);
    }
    __shared__ float ws[4], wq2[4];
    int wid = t >> 6, lane = t & 63;
    if (lane == 0) { ws[wid] = s; wq2[wid] = sq; }
    __syncthreads();
    if (t == 0) {
        float S = ws[0] + ws[1] + ws[2] + ws[3];
        float Q = wq2[0] + wq2[1] + wq2[2] + wq2[3];
        float m = S * (1.0f / CDIM);
        float var = Q * (1.0f / CDIM) - m * m;
        ws[0] = m;
        wq2[0] = rsqrtf(var + 1e-5f);
    }
    __syncthreads();
    float m = ws[0], inv = wq2[0];
    float y0 = (x0 - m) * inv * g[t] + b[t];
    float y1 = (x1 - m) * inv * g[t + 256] + b[t + 256];
    float y2 = (x2 - m) * inv * g[t + 512] + b[t + 512];
    if (outF) {
        float* orow = outF + (size_t)row * CDIM;
        orow[t] = y0; orow[t + 256] = y1; orow[t + 512] = y2;
    }
    if (outB) {
        short* orow = outB + (size_t)row * CDIM;
        orow[t] = f2bf(y0); orow[t + 256] = f2bf(y1); orow[t + 512] = f2bf(y2);
    }
}

extern "C" void kernel_launch(void* const* d_in, const int* in_sizes, int n_in,
                              void* d_out, int out_size, void* d_ws, size_t ws_size,
                              hipStream_t stream) {
    const float* dec = (const float*)d_in[0];
    const float* wq1 = (const float*)d_in[1]; const float* bq1 = (const float*)d_in[2];
    const float* wk1 = (const float*)d_in[3]; const float* bk1 = (const float*)d_in[4];
    const float* wv1 = (const float*)d_in[5]; const float* bv1 = (const float*)d_in[6];
    const float* wo1 = (const float*)d_in[7]; const float* bo1 = (const float*)d_in[8];
    const float* wq2 = (const float*)d_in[9]; const float* bq2 = (const float*)d_in[10];
    const float* wk2 = (const float*)d_in[11]; const float* bk2 = (const float*)d_in[12];
    const float* wv2 = (const float*)d_in[13]; const float* bv2 = (const float*)d_in[14];
    const float* wo2 = (const float*)d_in[15]; const float* bo2 = (const float*)d_in[16];
    const float* alphas1 = (const float*)d_in[17];
    const float* alphas2 = (const float*)d_in[18];
    const float* peg_w = (const float*)d_in[19]; const float* peg_b = (const float*)d_in[20];
    const float* ln1_g = (const float*)d_in[21]; const float* ln1_b = (const float*)d_in[22];
    const float* ln2_g = (const float*)d_in[23]; const float* ln2_b = (const float*)d_in[24];
    const float* cn_dw_w = (const float*)d_in[25]; const float* cn_dw_b = (const float*)d_in[26];
    const float* cn_ln_g = (const float*)d_in[27]; const float* cn_ln_b = (const float*)d_in[28];
    const float* cn_w1 = (const float*)d_in[29]; const float* cn_b1 = (const float*)d_in[30];
    const float* cn_w2 = (const float*)d_in[31]; const float* cn_b2 = (const float*)d_in[32];
    const float* cn_scale = (const float*)d_in[33]; const float* cn_alphas = (const float*)d_in[34];
    float* out = (float*)d_out;

    const size_t S = (size_t)BATCH * NTOK * CDIM;  // 6291456
    float* A0 = (float*)d_ws;
    float* A1 = A0 + S;
    short* Xb  = (short*)(A1 + S);
    short* QKV = Xb + S;            // [8192, 2304] bf16 packed q|k|v cols = 3*S
    short* Ob  = QKV + 3 * S;
    short* Hb  = Ob + S;            // 2*S bf16
    short* Wqkv1 = Hb + 2 * S;
    short* Wqkv2 = Wqkv1 + 2304 * 768;
    short* WoT1  = Wqkv2 + 2304 * 768;
    short* WoT2  = WoT1 + 768 * 768;
    short* W1T   = WoT2 + 768 * 768;
    short* W2T   = W1T + (size_t)3072 * 768;
    float* bqkv1 = (float*)(W2T + (size_t)768 * 3072);
    float* bqkv2 = bqkv1 + 2304;
    // MLP-time alias (QKV/Ob/Hb regions dead by then):
    short* Hfull = QKV + 2 * S;     // 8192x3072 bf16 = 4S shorts

    dim3 dwgrid(8, 12, 8);

    // ---- fused prep: all weight packing/transposes + bias pack + input transpose ----
    k_prep<<<dim3(12786), 256, 0, stream>>>(
        wq1, wk1, wv1, wq2, wk2, wv2, wo1, wo2, cn_w1, cn_w2,
        bq1, bk1, bv1, bq2, bk2, bv2, dec,
        Wqkv1, Wqkv2, WoT1, WoT2, W1T, W2T, bqkv1, bqkv2, A0, Xb);

    // ---- block 1 ----
    k_gemm_mfma<GM_BF16, 128><<<dim3(64, 18), 256, 0, stream>>>(
        Xb, Wqkv1, bqkv1, nullptr, nullptr, nullptr, nullptr, QKV, 8192, 2304, 768);
    k_attn_mfma<<<dim3(8, 12, 8), 256, 0, stream>>>(QKV, QKV + 768, QKV + 1536, Ob);
    k_gemm_mfma<GM_PROJ, 64><<<dim3(64, 12), 256, 0, stream>>>(
        Ob, WoT1, bo1, A0, alphas1, nullptr, A1, nullptr, 8192, 768, 768);
    k_dwconv_t<3><<<dwgrid, 256, 0, stream>>>(A1, peg_w, peg_b, A0);
    k_ln<<<8192, 256, 0, stream>>>(A0, ln1_g, ln1_b, A1, Xb);

    // ---- block 2 ----
    k_gemm_mfma<GM_BF16, 128><<<dim3(64, 18), 256, 0, stream>>>(
        Xb, Wqkv2, bqkv2, nullptr, nullptr, nullptr, nullptr, QKV, 8192, 2304, 768);
    k_attn_mfma<<<dim3(8, 12, 8), 256, 0, stream>>>(QKV, QKV + 768, QKV + 1536, Ob);
    k_gemm_mfma<GM_PROJ, 64><<<dim3(64, 12), 256, 0, stream>>>(
        Ob, WoT2, bo2, A1, alphas2, nullptr, A0, nullptr, 8192, 768, 768);
    k_ln<<<8192, 256, 0, stream>>>(A0, ln2_g, ln2_b, A1, nullptr);  // A1 = xln2 (kept)

    // ---- CNBlock head ----
    k_dwconv_t<7><<<dwgrid, 256, 0, stream>>>(A1, cn_dw_w, cn_dw_b, A0);
    k_ln<<<8192, 256, 0, stream>>>(A0, cn_ln_g, cn_ln_b, nullptr, Xb);
    // MLP, full M=8192; down-proj fused with layer-scale residual + output transpose
    k_gemm_mfma<GM_GELU, 128><<<dim3(64, 24), 256, 0, stream>>>(
        Xb, W1T, cn_b1, nullptr, nullptr, nullptr, nullptr, Hfull, 8192, 3072, 768);
    k_gemm_mfma<GM_FINAL, 64><<<dim3(64, 12), 256, 0, stream>>>(
        Hfull, W2T, cn_b2, A1, cn_scale, cn_alphas, out, nullptr, 8192, 768, 3072);
}

// Round 10
// 562.974 us; speedup vs baseline: 1.0390x; 1.0390x over previous
//
#include <hip/hip_runtime.h>
#include <math.h>

#define BATCH 8
#define CDIM 768
#define NTOK 1024
#define NH 12
#define HDIM 64
#define QKVN 2304

typedef __attribute__((ext_vector_type(8))) short bf16x8;
typedef __attribute__((ext_vector_type(4))) float f32x4;

__device__ inline short f2bf(float f) {
    union { float f; unsigned u; } v; v.f = f;
    unsigned r = (v.u + 0x7FFF + ((v.u >> 16) & 1)) >> 16;
    return (short)r;
}

__device__ inline unsigned pack2bf(float lo, float hi) {
    return (unsigned)(unsigned short)f2bf(lo) | ((unsigned)(unsigned short)f2bf(hi) << 16);
}

// async global->LDS DMA, 16 B per lane; lptr must be the WAVE-uniform base,
// lane l writes lptr + l*16 bytes (m97 pattern). Global src is per-lane.
__device__ inline void async_copy16(const short* g, short* l) {
    __builtin_amdgcn_global_load_lds(
        (const __attribute__((address_space(1))) void*)g,
        (__attribute__((address_space(3))) void*)l, 16, 0, 0);
}

// ---------------- fused prep: pack qkv weights + 4 weight transposes +
// bias pack + input transpose, one launch ----------------
__global__ __launch_bounds__(256) void k_prep(
    const float* __restrict__ wq1, const float* __restrict__ wk1, const float* __restrict__ wv1,
    const float* __restrict__ wq2, const float* __restrict__ wk2, const float* __restrict__ wv2,
    const float* __restrict__ wo1, const float* __restrict__ wo2,
    const float* __restrict__ cnw1, const float* __restrict__ cnw2,
    const float* __restrict__ bq1, const float* __restrict__ bk1, const float* __restrict__ bv1,
    const float* __restrict__ bq2, const float* __restrict__ bk2, const float* __restrict__ bv2,
    const float* __restrict__ dec,
    short* __restrict__ Wqkv1, short* __restrict__ Wqkv2,
    short* __restrict__ WoT1, short* __restrict__ WoT2,
    short* __restrict__ W1T, short* __restrict__ W2T,
    float* __restrict__ bqkv1, float* __restrict__ bqkv2,
    float* __restrict__ A0, short* __restrict__ Xb) {
    __shared__ float sh[64 * 65];
    int bid = blockIdx.x;
    int t = threadIdx.x;
    if (bid < 864) {
        // pack per-head qkv weights -> [2304,768] bf16
        int bx = bid % 12, z = bid / 12;
        int set = z / 36, rem = z % 36, sect = rem / 12, hh = rem % 12;
        const float* srcs[6] = {wq1, wk1, wv1, wq2, wk2, wv2};
        const float* src = srcs[set * 3 + sect] + (size_t)hh * 768 * 64;
        short* dst = (set ? Wqkv2 : Wqkv1) + ((size_t)sect * 768 + hh * 64) * 768;
        int k0 = bx * 64;
#pragma unroll
        for (int p = 0; p < 16; ++p) {
            int gid = t + p * 256;
            int r = gid >> 6, c = gid & 63;
            sh[r * 65 + c] = src[(size_t)(k0 + r) * 64 + c];
        }
        __syncthreads();
#pragma unroll
        for (int p = 0; p < 16; ++p) {
            int gid = t + p * 256;
            int d = gid >> 6, kk = gid & 63;
            dst[(size_t)d * 768 + k0 + kk] = f2bf(sh[kk * 65 + d]);
        }
    } else if (bid < 6624) {
        // weight transpose fp32 [R,C] -> bf16 [C,R]
        int r = bid - 864;
        const float* src; short* dst; int R, C, bx, by;
        if (r < 576)       { src = wo1;  dst = WoT1; R = 768;  C = 768;  bx = r % 24; by = r / 24; }
        else if (r < 1152) { int s = r - 576;  src = wo2;  dst = WoT2; R = 768;  C = 768;  bx = s % 24; by = s / 24; }
        else if (r < 3456) { int s = r - 1152; src = cnw1; dst = W1T;  R = 768;  C = 3072; bx = s % 96; by = s / 96; }
        else               { int s = r - 3456; src = cnw2; dst = W2T;  R = 3072; C = 768;  bx = s % 24; by = s / 24; }
        int c0 = bx * 32, r0 = by * 32, tx = t & 31, ty = t >> 5;
#pragma unroll
        for (int p = 0; p < 4; ++p)
            sh[(ty + p * 8) * 33 + tx] = src[(size_t)(r0 + ty + p * 8) * C + c0 + tx];
        __syncthreads();
#pragma unroll
        for (int p = 0; p < 4; ++p)
            dst[(size_t)(c0 + ty + p * 8) * R + r0 + tx] = f2bf(sh[tx * 33 + ty + p * 8]);
    } else if (bid < 6642) {
        // pack biases
        int tid = (bid - 6624) * 256 + t;
        if (tid < 4608) {
            int set = tid / 2304, n = tid % 2304;
            int sect = n / 768, rem = n % 768;
            const float* srcs[6] = {bq1, bk1, bv1, bq2, bk2, bv2};
            float v = srcs[set * 3 + sect][rem];
            (set ? bqkv2 : bqkv1)[n] = v;
        }
    } else {
        // transpose [B,C,N] -> [B,N,C], fp32 + bf16 mirror
        int r = bid - 6642;
        int bx = r % 32, by = (r / 32) % 24, bz = r / 768;
        int n0 = bx * 32, c0 = by * 32, tx = t & 31, ty = t >> 5;
#pragma unroll
        for (int p = 0; p < 4; ++p) {
            int c = c0 + ty + p * 8;
            sh[(ty + p * 8) * 33 + tx] = dec[((size_t)bz * CDIM + c) * NTOK + n0 + tx];
        }
        __syncthreads();
#pragma unroll
        for (int p = 0; p < 4; ++p) {
            int n = n0 + ty + p * 8;
            float val = sh[tx * 33 + ty + p * 8];
            size_t idx = ((size_t)bz * NTOK + n) * CDIM + c0 + tx;
            A0[idx] = val;
            Xb[idx] = f2bf(val);
        }
    }
}

// ---------------- generic bf16 MFMA GEMM, 128xBN tile, BK=32 ----------------
// Single-barrier double-buffered DMA pipeline: barrier drains stage st's DMA,
// then DMA for k+32 into stage st^1 flies DURING the MFMA burst on stage st.
// LDS rows are chunk-XOR-swizzled (rule 21): thread stages global chunk
// (ci ^ ((row>>1)&3)) linearly; reads XOR the same -> conflict-free b128.
// A [M,K] bf16 row-major; Bt [N,K] bf16 row-major (i.e. B transposed)
#define GM_FINAL 0
#define GM_PROJ  1
#define GM_GELU  2
#define GM_BF16  3

template<int MODE, int BN>
__global__ __launch_bounds__(256) void k_gemm_mfma(
    const short* __restrict__ A, const short* __restrict__ Bt,
    const float* __restrict__ bias, const float* __restrict__ resid,
    const float* __restrict__ rscale, const float* __restrict__ alph,
    float* __restrict__ outF, short* __restrict__ outB, int M, int N, int K) {
    constexpr int NT = BN / 32;   // 16-col tiles per wave
    constexpr int BP = BN / 64;   // B staging passes per 32-chunk
    constexpr int STAGE = 2 * 128 * 32 + 2 * BN * 32;            // shorts (2 stages)
    constexpr int FINALS = (MODE == GM_FINAL) ? 64 * 132 * 2 : 0; // shorts (64 cols x 132-stride floats)
    constexpr int SMEM = STAGE > FINALS ? STAGE : FINALS;
    __shared__ short smem[SMEM];
    short* As = smem;                     // [2][128][32]
    short* Bs = smem + 2 * 128 * 32;      // [2][BN][32]
    int t = threadIdx.x;
    int w = t >> 6, lane = t & 63, l15 = lane & 15, quad = lane >> 4;
    int r0 = blockIdx.x * 128, n0 = blockIdx.y * BN;
    int wr = (w >> 1) * 64, wc = (w & 1) * (BN / 2);
    f32x4 acc[4][NT];
#pragma unroll
    for (int i = 0; i < 4; ++i)
#pragma unroll
        for (int j = 0; j < NT; ++j) acc[i][j] = (f32x4){0.f, 0.f, 0.f, 0.f};
    // staging: row = t>>2, chunk = t&3, source chunk XOR-swizzled by (row>>1)&3
    int sr = t >> 2, sc = ((t & 3) ^ ((sr >> 1) & 3)) * 8;
    const short* Ag = A + (size_t)(r0 + sr) * K + sc;
    const short* Bg = Bt + (size_t)(n0 + sr) * K + sc;
    short* AsW = As + w * 512;   // wave-uniform base: lane l -> + l*8 shorts (16 B)
    short* BsW = Bs + w * 512;
    // read-side swizzle: physical chunk = quad ^ ((l15>>1)&3)
    int rsw = ((quad ^ ((l15 >> 1) & 3)) << 3);
    // preload chunk 0 into stage 0
#pragma unroll
    for (int p = 0; p < 2; ++p)
        async_copy16(Ag + (size_t)p * 64 * K, AsW + p * 2048);
#pragma unroll
    for (int p = 0; p < BP; ++p)
        async_copy16(Bg + (size_t)p * 64 * K, BsW + p * 2048);
    int st = 0;
    for (int k0 = 0; k0 < K; k0 += 32, st ^= 1) {
        __syncthreads();   // drains stage-st DMA; prior stage reads complete
        if (k0 + 32 < K) {
            int nst = st ^ 1;
#pragma unroll
            for (int p = 0; p < 2; ++p)
                async_copy16(Ag + k0 + 32 + (size_t)p * 64 * K,
                             AsW + nst * 4096 + p * 2048);
#pragma unroll
            for (int p = 0; p < BP; ++p)
                async_copy16(Bg + k0 + 32 + (size_t)p * 64 * K,
                             BsW + nst * (BN * 32) + p * 2048);
        }
        bf16x8 af[4], bf[NT];
#pragma unroll
        for (int i = 0; i < 4; ++i)
            af[i] = *(const bf16x8*)&As[st * 4096 + (wr + i * 16 + l15) * 32 + rsw];
#pragma unroll
        for (int j = 0; j < NT; ++j)
            bf[j] = *(const bf16x8*)&Bs[st * (BN * 32) + (wc + j * 16 + l15) * 32 + rsw];
#pragma unroll
        for (int i = 0; i < 4; ++i)
#pragma unroll
            for (int j = 0; j < NT; ++j)
                acc[i][j] = __builtin_amdgcn_mfma_f32_16x16x32_bf16(af[i], bf[j], acc[i][j], 0, 0, 0);
    }
    if (MODE == GM_FINAL) {
        // fused: val = rscale*val(+bias) + alph*resid; write transposed [B,C,N] via LDS
        __syncthreads();
        float* T = (float*)smem;
#pragma unroll
        for (int i = 0; i < 4; ++i)
#pragma unroll
            for (int j = 0; j < NT; ++j)
#pragma unroll
                for (int rr = 0; rr < 4; ++rr) {
                    int rl = wr + i * 16 + quad * 4 + rr;   // 0..127
                    int cl = wc + j * 16 + l15;             // 0..63
                    int row = r0 + rl, col = n0 + cl;
                    float val = acc[i][j][rr] + bias[col];
                    val = rscale[col] * val + alph[col] * resid[(size_t)row * N + col];
                    T[cl * 132 + rl] = val;
                }
        __syncthreads();
        int c = t >> 2, qo = (t & 3) * 32;
        int b = r0 >> 10, tokbase = r0 & 1023;
        float* obase = outF + ((size_t)(b * 768 + n0 + c)) * 1024 + tokbase + qo;
#pragma unroll
        for (int ii = 0; ii < 8; ++ii)
            *(float4*)&obase[ii * 4] = *(float4*)&T[c * 132 + qo + ii * 4];
        return;
    }
#pragma unroll
    for (int i = 0; i < 4; ++i)
#pragma unroll
        for (int j = 0; j < NT; ++j)
#pragma unroll
            for (int rr = 0; rr < 4; ++rr) {
                int row = r0 + wr + i * 16 + quad * 4 + rr;
                int col = n0 + wc + j * 16 + l15;
                float val = acc[i][j][rr] + bias[col];
                if (MODE == GM_PROJ) {
                    val += rscale[col] * resid[(size_t)row * N + col];
                    outF[(size_t)row * N + col] = val;
                } else if (MODE == GM_GELU) {
                    // tanh-form GELU via hw exp2/rcp: x*sigmoid(1.595769*(x+0.044715x^3))
                    float u = val * (1.0f + 0.044715f * val * val);
                    float zz = __builtin_amdgcn_rcpf(
                        1.0f + __builtin_amdgcn_exp2f(-2.3022082f * u));
                    outB[(size_t)row * N + col] = f2bf(val * zz);
                } else {  // GM_BF16: plain bf16 row-major C
                    outB[(size_t)row * N + col] = f2bf(val);
                }
            }
}

// ---------------- MFMA sigmoid attention, v4 ----------------
// per (b,h): O = sigmoid(QK^T/8) V ; q/k/v = column sections of the packed
// [B*N, 2304] QKV matrix (row stride 2304); O -> [B,N,C] bf16
// Swapped-operand S^T = K Q^T so each lane holds 4 CONSECUTIVE keys of one
// q-row -> packed u32 P writes into wave-private LDS rows (no barrier).
// Async swizzled K staging (dbuf), V reg-prefetch + dbuf, 1 barrier/iter.
__global__ __launch_bounds__(256, 3) void k_attn_mfma(
    const short* __restrict__ q, const short* __restrict__ k,
    const short* __restrict__ v, short* __restrict__ o) {
    __shared__ short Ks[2][64 * 64];   // chunk16B c holds logical chunk c^(row&7)
    __shared__ short Vt[2][64][72];    // V^T [d][tok], padded
    __shared__ short Ps[128][72];      // P [q][key], rows wave-private
    int t = threadIdx.x;
    int w = t >> 6, lane = t & 63, l15 = lane & 15, quad = lane >> 4;
    // XCD-aware remap: all 8 q-blocks of one (b,h) land on one XCD (flat%8);
    // each XCD owns one batch -> K/V rows (shared across heads) stay in its L2
    int flat = blockIdx.x + (blockIdx.y << 3) + blockIdx.z * 96;
    int xcd = flat & 7, slot = flat >> 3;
    int qb = slot & 7, grp = xcd * 12 + (slot >> 3);
    int h = grp % 12, b = grp / 12;
    int q0 = qb * 128;
    size_t base = ((size_t)b * NTOK) * QKVN + h * 64;
    const short* qp = q + base;
    const short* kp = k + base;
    const short* vp = v + base;

    // Q fragments, held for the whole loop (B-operand of S^T)
    bf16x8 qf[2][2];
#pragma unroll
    for (int nq = 0; nq < 2; ++nq)
#pragma unroll
        for (int kc = 0; kc < 2; ++kc)
            qf[nq][kc] = *(const bf16x8*)&qp[(size_t)(q0 + w * 32 + nq * 16 + l15) * QKVN + kc * 32 + quad * 8];

    // K DMA: pre-swizzled per-lane global source, linear LDS dest (rule 21)
    int r8 = lane >> 3;
    const short* kg = kp + (size_t)r8 * QKVN + (((lane & 7) ^ r8) << 3);
    int vtok = t & 63, vd0 = (t >> 6) * 8;

    f32x4 oacc[4][2];
#pragma unroll
    for (int dt = 0; dt < 4; ++dt)
#pragma unroll
        for (int nq = 0; nq < 2; ++nq) oacc[dt][nq] = (f32x4){0.f, 0.f, 0.f, 0.f};

    // prologue: stage tile 0 into buffer 0
#pragma unroll
    for (int p = 0; p < 2; ++p)
        async_copy16(kg + (size_t)(p * 32 + w * 8) * QKVN, &Ks[0][(p * 32 + w * 8) * 64]);
    {
        bf16x8 v0 = *(const bf16x8*)&vp[(size_t)vtok * QKVN + vd0];
        bf16x8 v1 = *(const bf16x8*)&vp[(size_t)vtok * QKVN + vd0 + 32];
#pragma unroll
        for (int j = 0; j < 8; ++j) {
            Vt[0][vd0 + j][vtok] = v0[j];
            Vt[0][vd0 + 32 + j][vtok] = v1[j];
        }
    }

    short* prow0 = &Ps[w * 32 + l15][0];         // nq=0 row
    short* prow1 = &Ps[w * 32 + 16 + l15][0];    // nq=1 row

    for (int kt = 0; kt < 16; ++kt) {
        int cur = kt & 1, nxt = cur ^ 1;
        __syncthreads();   // drains K DMA(cur); V(cur) writes visible; prior-buf reads done
        bf16x8 vv0, vv1;
        if (kt < 15) {
            const short* kgn = kg + (size_t)((kt + 1) * 64) * QKVN;
#pragma unroll
            for (int p = 0; p < 2; ++p)
                async_copy16(kgn + (size_t)(p * 32 + w * 8) * QKVN, &Ks[nxt][(p * 32 + w * 8) * 64]);
            vv0 = *(const bf16x8*)&vp[((size_t)((kt + 1) * 64 + vtok)) * QKVN + vd0];
            vv1 = *(const bf16x8*)&vp[((size_t)((kt + 1) * 64 + vtok)) * QKVN + vd0 + 32];
        }
        // S^T = K Q^T : rows = keys (64), cols = this wave's 32 q-rows
        f32x4 sacc[4][2];
#pragma unroll
        for (int mk = 0; mk < 4; ++mk)
#pragma unroll
            for (int nq = 0; nq < 2; ++nq) sacc[mk][nq] = (f32x4){0.f, 0.f, 0.f, 0.f};
        __builtin_amdgcn_s_setprio(1);
#pragma unroll
        for (int mk = 0; mk < 4; ++mk)
#pragma unroll
            for (int kc = 0; kc < 2; ++kc) {
                bf16x8 kf = *(const bf16x8*)&Ks[cur][(mk * 16 + l15) * 64 + (((kc * 4 + quad) ^ (l15 & 7)) << 3)];
#pragma unroll
                for (int nq = 0; nq < 2; ++nq)
                    sacc[mk][nq] = __builtin_amdgcn_mfma_f32_16x16x32_bf16(kf, qf[nq][kc], sacc[mk][nq], 0, 0, 0);
            }
        __builtin_amdgcn_s_setprio(0);
        // sigmoid -> Ps[q][key]: lane holds keys mk*16+quad*4+rr of q-col
        // nq*16+l15 -> 4 consecutive keys = two packed u32 writes
#pragma unroll
        for (int mk = 0; mk < 4; ++mk)
#pragma unroll
            for (int nq = 0; nq < 2; ++nq) {
                float z[4];
#pragma unroll
                for (int rr = 0; rr < 4; ++rr)
                    z[rr] = __builtin_amdgcn_rcpf(
                        1.0f + __builtin_amdgcn_exp2f(sacc[mk][nq][rr] * -0.18033688011112042f));
                unsigned* pw = (unsigned*)((nq ? prow1 : prow0) + mk * 16 + quad * 4);
                pw[0] = pack2bf(z[0], z[1]);
                pw[1] = pack2bf(z[2], z[3]);
            }
        // scatter V(next) to LDS (loads issued at iter top -> latency hidden)
        if (kt < 15) {
#pragma unroll
            for (int j = 0; j < 8; ++j) {
                Vt[nxt][vd0 + j][vtok] = vv0[j];
                Vt[nxt][vd0 + 32 + j][vtok] = vv1[j];
            }
        }
        // in-wave fence: Ps rows are wave-private, but lanes read other
        // lanes' writes -> drain this wave's DS ops (no block barrier needed)
        asm volatile("s_waitcnt lgkmcnt(0)" ::: "memory");
        __builtin_amdgcn_sched_barrier(0);
        bf16x8 pf[2][2];
#pragma unroll
        for (int kc = 0; kc < 2; ++kc)
#pragma unroll
            for (int nq = 0; nq < 2; ++nq)
                pf[kc][nq] = *(const bf16x8*)((nq ? prow1 : prow0) + kc * 32 + quad * 8);
        // O^T += V^T P^T
        __builtin_amdgcn_s_setprio(1);
#pragma unroll
        for (int dt = 0; dt < 4; ++dt)
#pragma unroll
            for (int kc = 0; kc < 2; ++kc) {
                bf16x8 vf = *(const bf16x8*)&Vt[cur][dt * 16 + l15][kc * 32 + quad * 8];
#pragma unroll
                for (int nq = 0; nq < 2; ++nq)
                    oacc[dt][nq] = __builtin_amdgcn_mfma_f32_16x16x32_bf16(vf, pf[kc][nq], oacc[dt][nq], 0, 0, 0);
            }
        __builtin_amdgcn_s_setprio(0);
    }
    // epilogue: O^T[d = dt*16+quad*4+rr][q = w*32+nq*16+l15] -> o[b,tok,h*64+d]
#pragma unroll
    for (int dt = 0; dt < 4; ++dt)
#pragma unroll
        for (int nq = 0; nq < 2; ++nq) {
            int tok = q0 + w * 32 + nq * 16 + l15;
            int c = h * 64 + dt * 16 + quad * 4;
            unsigned* op = (unsigned*)&o[((size_t)b * NTOK + tok) * CDIM + c];
            op[0] = pack2bf(oacc[dt][nq][0], oacc[dt][nq][1]);
            op[1] = pack2bf(oacc[dt][nq][2], oacc[dt][nq][3]);
        }
}

// ---------------- depthwise conv, register sliding window (fp32) ----------------
template<int K>
__global__ __launch_bounds__(256) void k_dwconv_t(
    const float* __restrict__ in, const float* __restrict__ w,
    const float* __restrict__ bias, float* __restrict__ out) {
    constexpr int PAD = K / 2;
    constexpr int KK = K * K;
    int t = threadIdx.x;
    int c = blockIdx.y * 64 + (t & 63);
    int j = blockIdx.x * 4 + (t >> 6);
    int b = blockIdx.z;
    float wr[KK];
#pragma unroll
    for (int qq = 0; qq < KK; ++qq) wr[qq] = w[(size_t)c * KK + qq];
    float bsv = bias[c];
    const float* base = in + (size_t)b * NTOK * CDIM + c;
    float win[K][K];
#pragma unroll
    for (int s = 1; s < K; ++s) {
        int ii = s - 1 - PAD;
#pragma unroll
        for (int qq = 0; qq < K; ++qq) {
            int jj = j - PAD + qq;
            win[s][qq] = (ii >= 0 && jj >= 0 && jj < 32)
                         ? base[(size_t)(ii * 32 + jj) * CDIM] : 0.0f;
        }
    }
#pragma unroll
    for (int i = 0; i < 32; ++i) {
#pragma unroll
        for (int r = 0; r < K - 1; ++r)
#pragma unroll
            for (int qq = 0; qq < K; ++qq) win[r][qq] = win[r + 1][qq];
        int ii = i + PAD;
#pragma unroll
        for (int qq = 0; qq < K; ++qq) {
            int jj = j - PAD + qq;
            win[K - 1][qq] = (ii < 32 && jj >= 0 && jj < 32)
                             ? base[(size_t)(ii * 32 + jj) * CDIM] : 0.0f;
        }
        float acc = bsv;
#pragma unroll
        for (int r = 0; r < K; ++r)
#pragma unroll
            for (int qq = 0; qq < K; ++qq)
                acc = fmaf(win[r][qq], wr[r * K + qq], acc);
        out[((size_t)b * NTOK + i * 32 + j) * CDIM + c] = acc;
    }
}

// ---------------- layernorm over C=768, nullable fp32/bf16 outputs ----------------
__global__ __launch_bounds__(256) void k_ln(
    const float* __restrict__ in, const float* __restrict__ g,
    const float* __restrict__ b, float* __restrict__ outF, short* __restrict__ outB) {
    int row = blockIdx.x;
    const float* xr = in + (size_t)row * CDIM;
    int t = threadIdx.x;
    float x0 = xr[t], x1 = xr[t + 256], x2 = xr[t + 512];
    float s = x0 + x1 + x2;
    float sq = x0 * x0 + x1 * x1 + x2 * x2;
#pragma unroll
    for (int off = 32; off > 0; off >>= 1) {
        s += __shfl_down(s, off);
        sq += __shfl_down(sq, off);
    }
    __shared__ float ws[4], wq2[4];
    int wid = t >> 6, lane = t & 63;
    if (lane == 0) { ws[wid] = s; wq2[wid] = sq; }
    __syncthreads();
    if (t == 0) {
        float S = ws[0] + ws[1] + ws[2] + ws[3];
        float Q = wq2[0] + wq2[1] + wq2[2] + wq2[3];
        float m = S * (1.0f / CDIM);
        float var = Q * (1.0f / CDIM) - m * m;
        ws[0] = m;
        wq2[0] = rsqrtf(var + 1e-5f);
    }
    __syncthreads();
    float m = ws[0], inv = wq2[0];
    float y0 = (x0 - m) * inv * g[t] + b[t];
    float y1 = (x1 - m) * inv * g[t + 256] + b[t + 256];
    float y2 = (x2 - m) * inv * g[t + 512] + b[t + 512];
    if (outF) {
        float* orow = outF + (size_t)row * CDIM;
        orow[t] = y0; orow[t + 256] = y1; orow[t + 512] = y2;
    }
    if (outB) {
        short* orow = outB + (size_t)row * CDIM;
        orow[t] = f2bf(y0); orow[t + 256] = f2bf(y1); orow[t + 512] = f2bf(y2);
    }
}

extern "C" void kernel_launch(void* const* d_in, const int* in_sizes, int n_in,
                              void* d_out, int out_size, void* d_ws, size_t ws_size,
                              hipStream_t stream) {
    const float* dec = (const float*)d_in[0];
    const float* wq1 = (const float*)d_in[1]; const float* bq1 = (const float*)d_in[2];
    const float* wk1 = (const float*)d_in[3]; const float* bk1 = (const float*)d_in[4];
    const float* wv1 = (const float*)d_in[5]; const float* bv1 = (const float*)d_in[6];
    const float* wo1 = (const float*)d_in[7]; const float* bo1 = (const float*)d_in[8];
    const float* wq2 = (const float*)d_in[9]; const float* bq2 = (const float*)d_in[10];
    const float* wk2 = (const float*)d_in[11]; const float* bk2 = (const float*)d_in[12];
    const float* wv2 = (const float*)d_in[13]; const float* bv2 = (const float*)d_in[14];
    const float* wo2 = (const float*)d_in[15]; const float* bo2 = (const float*)d_in[16];
    const float* alphas1 = (const float*)d_in[17];
    const float* alphas2 = (const float*)d_in[18];
    const float* peg_w = (const float*)d_in[19]; const float* peg_b = (const float*)d_in[20];
    const float* ln1_g = (const float*)d_in[21]; const float* ln1_b = (const float*)d_in[22];
    const float* ln2_g = (const float*)d_in[23]; const float* ln2_b = (const float*)d_in[24];
    const float* cn_dw_w = (const float*)d_in[25]; const float* cn_dw_b = (const float*)d_in[26];
    const float* cn_ln_g = (const float*)d_in[27]; const float* cn_ln_b = (const float*)d_in[28];
    const float* cn_w1 = (const float*)d_in[29]; const float* cn_b1 = (const float*)d_in[30];
    const float* cn_w2 = (const float*)d_in[31]; const float* cn_b2 = (const float*)d_in[32];
    const float* cn_scale = (const float*)d_in[33]; const float* cn_alphas = (const float*)d_in[34];
    float* out = (float*)d_out;

    const size_t S = (size_t)BATCH * NTOK * CDIM;  // 6291456
    float* A0 = (float*)d_ws;
    float* A1 = A0 + S;
    short* Xb  = (short*)(A1 + S);
    short* QKV = Xb + S;            // [8192, 2304] bf16 packed q|k|v cols = 3*S
    short* Ob  = QKV + 3 * S;
    short* Hb  = Ob + S;            // 2*S bf16
    short* Wqkv1 = Hb + 2 * S;
    short* Wqkv2 = Wqkv1 + 2304 * 768;
    short* WoT1  = Wqkv2 + 2304 * 768;
    short* WoT2  = WoT1 + 768 * 768;
    short* W1T   = WoT2 + 768 * 768;
    short* W2T   = W1T + (size_t)3072 * 768;
    float* bqkv1 = (float*)(W2T + (size_t)768 * 3072);
    float* bqkv2 = bqkv1 + 2304;
    // MLP-time alias (QKV/Ob/Hb regions dead by then):
    short* Hfull = QKV + 2 * S;     // 8192x3072 bf16 = 4S shorts

    dim3 dwgrid(8, 12, 8);

    // ---- fused prep: all weight packing/transposes + bias pack + input transpose ----
    k_prep<<<dim3(12786), 256, 0, stream>>>(
        wq1, wk1, wv1, wq2, wk2, wv2, wo1, wo2, cn_w1, cn_w2,
        bq1, bk1, bv1, bq2, bk2, bv2, dec,
        Wqkv1, Wqkv2, WoT1, WoT2, W1T, W2T, bqkv1, bqkv2, A0, Xb);

    // ---- block 1 ----
    k_gemm_mfma<GM_BF16, 128><<<dim3(64, 18), 256, 0, stream>>>(
        Xb, Wqkv1, bqkv1, nullptr, nullptr, nullptr, nullptr, QKV, 8192, 2304, 768);
    k_attn_mfma<<<dim3(8, 12, 8), 256, 0, stream>>>(QKV, QKV + 768, QKV + 1536, Ob);
    k_gemm_mfma<GM_PROJ, 64><<<dim3(64, 12), 256, 0, stream>>>(
        Ob, WoT1, bo1, A0, alphas1, nullptr, A1, nullptr, 8192, 768, 768);
    k_dwconv_t<3><<<dwgrid, 256, 0, stream>>>(A1, peg_w, peg_b, A0);
    k_ln<<<8192, 256, 0, stream>>>(A0, ln1_g, ln1_b, A1, Xb);

    // ---- block 2 ----
    k_gemm_mfma<GM_BF16, 128><<<dim3(64, 18), 256, 0, stream>>>(
        Xb, Wqkv2, bqkv2, nullptr, nullptr, nullptr, nullptr, QKV, 8192, 2304, 768);
    k_attn_mfma<<<dim3(8, 12, 8), 256, 0, stream>>>(QKV, QKV + 768, QKV + 1536, Ob);
    k_gemm_mfma<GM_PROJ, 64><<<dim3(64, 12), 256, 0, stream>>>(
        Ob, WoT2, bo2, A1, alphas2, nullptr, A0, nullptr, 8192, 768, 768);
    k_ln<<<8192, 256, 0, stream>>>(A0, ln2_g, ln2_b, A1, nullptr);  // A1 = xln2 (kept)

    // ---- CNBlock head ----
    k_dwconv_t<7><<<dwgrid, 256, 0, stream>>>(A1, cn_dw_w, cn_dw_b, A0);
    k_ln<<<8192, 256, 0, stream>>>(A0, cn_ln_g, cn_ln_b, nullptr, Xb);
    // MLP, full M=8192; down-proj fused with layer-scale residual + output transpose
    k_gemm_mfma<GM_GELU, 128><<<dim3(64, 24), 256, 0, stream>>>(
        Xb, W1T, cn_b1, nullptr, nullptr, nullptr, nullptr, Hfull, 8192, 3072, 768);
    k_gemm_mfma<GM_FINAL, 64><<<dim3(64, 12), 256, 0, stream>>>(
        Hfull, W2T, cn_b2, A1, cn_scale, cn_alphas, out, nullptr, 8192, 768, 3072);
}